// Round 1
// baseline (299.114 us; speedup 1.0000x reference)
//
#include <hip/hip_runtime.h>
#include <hip/hip_bf16.h>
#include <stdint.h>

// Fully-connected tensor product as a set of on-the-fly-A GEMMs in bf16 MFMA.
// A[b,(u,v)] = a_plane[b,u] * b_plane[b,v] generated in-register; B = retiled weights.
// ws holds bf16-retiled weights (MFMA-fragment-native [tile][q][n][8]) and x planes
// ([octet][row][8] per 128-row tile) so all LDS staging is pure global_load_lds and
// all LDS reads are <=2-way-conflict ds_read_b128 / ds_read_u16.

typedef unsigned short u16_t;
typedef short short8 __attribute__((ext_vector_type(8)));
typedef float f32x4 __attribute__((ext_vector_type(4)));

#define SZ_W000  (2u*512u*2048u)
#define SZ_W110  (2u*128u*2048u)
#define SZ_W011  (256u*2048u)
#define SZ_W101  (256u*2048u)
#define SZ_W111  (128u*2048u)
#define SZ_XS    (64u*16u*128u*8u)
#define SZ_XV    (64u*3u*8u*128u*8u)
#define OFF_W000 0u
#define OFF_W110 (OFF_W000+SZ_W000)
#define OFF_W011 (OFF_W110+SZ_W110)
#define OFF_W101 (OFF_W011+SZ_W011)
#define OFF_W111 (OFF_W101+SZ_W101)
#define OFF_XS1  (OFF_W111+SZ_W111)
#define OFF_XV1  (OFF_XS1+SZ_XS)
#define OFF_XS2  (OFF_XV1+SZ_XV)
#define OFF_XV2  (OFF_XS2+SZ_XS)
#define WS_USHORTS (OFF_XV2+SZ_XV)

__device__ __forceinline__ u16_t f2bf(float f){
  union{float f;unsigned u;}a; a.f=f;
  return (u16_t)((a.u + 0x7fffu + ((a.u>>16)&1u))>>16);   // RNE
}
__device__ __forceinline__ float bf2f(u16_t s){
  union{unsigned u;float f;}a; a.u=((unsigned)s)<<16; return a.f;
}

// ---------------- pre-kernels: retile to bf16 in ws ----------------
__global__ void tile_weights_k(const float* __restrict__ w000, const float* __restrict__ w011,
                               const float* __restrict__ w101, const float* __restrict__ w110,
                               const float* __restrict__ w111, u16_t* __restrict__ ws)
{
  unsigned tid = blockIdx.x*256u + threadIdx.x;
  if (tid < SZ_W000) {  // [h][g=u*4+vb][q][n][e], v = vb*32+q*8+e
    unsigned e=tid&7u, n=(tid>>3)&63u, q=(tid>>9)&3u, g=(tid>>11)&511u, h=tid>>20;
    unsigned u=g>>2, v=((g&3u)<<5)+(q<<3)+e;
    ws[OFF_W000+tid] = f2bf(w000[u*16384u + v*128u + (h<<6) + n]);
    return;
  }
  tid -= SZ_W000;
  if (tid < SZ_W110) {  // 1/sqrt(3) folded
    unsigned e=tid&7u, n=(tid>>3)&63u, q=(tid>>9)&3u, g=(tid>>11)&127u, h=tid>>18;
    unsigned u=g>>1, v=((g&1u)<<5)+(q<<3)+e;
    ws[OFF_W110+tid] = f2bf(w110[u*8192u + v*128u + (h<<6) + n] * 0.5773502691896258f);
    return;
  }
  tid -= SZ_W110;
  if (tid < SZ_W011) {
    unsigned e=tid&7u, n=(tid>>3)&63u, q=(tid>>9)&3u, g=(tid>>11)&255u;
    unsigned u=g>>1, v=((g&1u)<<5)+(q<<3)+e;
    ws[OFF_W011+tid] = f2bf(w011[u*4096u + v*64u + n]);
    return;
  }
  tid -= SZ_W011;
  if (tid < SZ_W101) {  // k = s2idx*64 + v1idx  (transposed vs natural)
    unsigned e=tid&7u, n=(tid>>3)&63u, q=(tid>>9)&3u, g=(tid>>11)&255u;
    unsigned s2i=g>>1, v1i=((g&1u)<<5)+(q<<3)+e;
    ws[OFF_W101+tid] = f2bf(w101[v1i*8192u + s2i*64u + n]);
    return;
  }
  tid -= SZ_W101;
  {
    unsigned e=tid&7u, n=(tid>>3)&63u, q=(tid>>9)&3u, g=(tid>>11)&127u;
    unsigned u=g>>1, v=((g&1u)<<5)+(q<<3)+e;
    ws[OFF_W111+tid] = f2bf(w111[u*4096u + v*64u + n]);
  }
}

__global__ void tile_x_k(const float* __restrict__ x1, const float* __restrict__ x2,
                         u16_t* __restrict__ ws)
{
  unsigned tid = blockIdx.x*256u + threadIdx.x;
  if (tid < SZ_XS) {                // xs1: [rt][ou][r][e]
    unsigned e=tid&7u, r=(tid>>3)&127u, ou=(tid>>10)&15u, rt=tid>>14;
    ws[OFF_XS1+tid] = f2bf(x1[(rt*128u+r)*320u + (ou<<3) + e]);
    return;
  }
  tid -= SZ_XS;
  if (tid < SZ_XV) {                // xv1: [rt][i][ov][r][e]
    unsigned e=tid&7u, r=(tid>>3)&127u, ov=(tid>>10)&7u, rest=tid>>13;
    unsigned i=rest%3u, rt=rest/3u;
    ws[OFF_XV1+tid] = f2bf(x1[(rt*128u+r)*320u + 128u + ((ov<<3)+e)*3u + i]);
    return;
  }
  tid -= SZ_XV;
  if (tid < SZ_XS) {
    unsigned e=tid&7u, r=(tid>>3)&127u, ou=(tid>>10)&15u, rt=tid>>14;
    ws[OFF_XS2+tid] = f2bf(x2[(rt*128u+r)*320u + (ou<<3) + e]);
    return;
  }
  tid -= SZ_XS;
  {
    unsigned e=tid&7u, r=(tid>>3)&127u, ov=(tid>>10)&7u, rest=tid>>13;
    unsigned i=rest%3u, rt=rest/3u;
    ws[OFF_XV2+tid] = f2bf(x2[(rt*128u+r)*320u + 128u + ((ov<<3)+e)*3u + i]);
  }
}

__global__ void zero_out0_k(float* __restrict__ out)
{
  unsigned tid = blockIdx.x*256u + threadIdx.x;     // 8192*128 threads
  out[(tid>>7)*512u + (tid&127u)] = 0.f;
}

// ---------------- main kernel ----------------
#define GLD16(g,l) __builtin_amdgcn_global_load_lds( \
    (const __attribute__((address_space(1))) unsigned int*)(g), \
    (__attribute__((address_space(3))) unsigned int*)(l), 16, 0, 0)

__device__ __forceinline__ void stageB(const u16_t* tile, u16_t* lds, int wid, int lane){
  GLD16((const char*)tile + wid*1024 + lane*16, (char*)lds + wid*1024);
}
__device__ __forceinline__ void stagePlane(const u16_t* src, u16_t* dst, int nbytes, int wid, int lane){
  for (int c = wid; c*1024 < nbytes; c += 4)
    GLD16((const char*)src + c*1024 + lane*16, (char*)dst + c*1024);
}

// One phase: acc += A_phase * W_phase.  steps = U*2 K-steps of 32.
// a-plane: [U/8][128][8] bf16 (scalar per step), b-plane: [8][128][8] (V=64 in LDS).
// B tile t is ws tile ((t>>1)*ustride + (t&1)) from Wt.
__device__ __forceinline__ void run_phase(const u16_t* __restrict__ Wt, int ustride, int steps,
    const u16_t* __restrict__ aSrc, int aBytes, const u16_t* __restrict__ bSrc, bool neg,
    u16_t* sA, u16_t* sBp, u16_t* sW, f32x4 (&acc)[2][4])
{
  const int lane = threadIdx.x & 63, wid = threadIdx.x >> 6;
  const int q = lane >> 4, r15 = lane & 15;

  stagePlane(aSrc, sA, aBytes, wid, lane);
  stagePlane(bSrc, sBp, 16384, wid, lane);
  stageB(Wt,        sW,        wid, lane);          // tile(0)=0
  stageB(Wt + 2048, sW + 2048, wid, lane);          // tile(1)=1
  asm volatile("s_waitcnt vmcnt(0)" ::: "memory");
  __builtin_amdgcn_s_barrier();
  __builtin_amdgcn_sched_barrier(0);

  int bufc = 0;
  for (int t = 0; t < steps; ++t) {
    // own chunk of tile t landed (counted wait: tile t+1 may stay in flight)
    if (t < steps-1) { asm volatile("s_waitcnt vmcnt(1)" ::: "memory"); }
    else             { asm volatile("s_waitcnt vmcnt(0)" ::: "memory"); }
    __builtin_amdgcn_s_barrier();
    __builtin_amdgcn_sched_barrier(0);
    if (t + 2 < steps) {                            // prefetch tile t+2
      int bn = bufc + 2; if (bn >= 3) bn -= 3;
      int tl = ((t+2)>>1)*ustride + ((t+2)&1);
      stageB(Wt + tl*2048, sW + bn*2048, wid, lane);
    }
    const u16_t* W = sW + bufc*2048;
    const int u = t >> 1;
    const int ovb = ((t & 1) << 2) + q;
    short8 afr[2];
#pragma unroll
    for (int mt = 0; mt < 2; ++mt) {
      const int r = (wid<<5) + (mt<<4) + r15;
      float av = bf2f(sA[((u>>3)<<10) + (r<<3) + (u&7)]);
      av = neg ? -av : av;
      short8 bv = *(const short8*)(sBp + (ovb<<10) + (r<<3));
      short8 af;
#pragma unroll
      for (int e = 0; e < 8; ++e) af[e] = (short)f2bf(av * bf2f((u16_t)bv[e]));
      afr[mt] = af;
    }
#pragma unroll
    for (int nt = 0; nt < 4; ++nt) {
      short8 bw = *(const short8*)(W + (q<<9) + ((((nt<<4)+r15))<<3));
#pragma unroll
      for (int mt = 0; mt < 2; ++mt)
        acc[mt][nt] = __builtin_amdgcn_mfma_f32_16x16x32_bf16(afr[mt], bw, acc[mt][nt], 0, 0, 0);
    }
    bufc = (bufc==2) ? 0 : bufc+1;
  }
  __builtin_amdgcn_s_barrier();   // protect LDS before next phase restages
}

__global__ __launch_bounds__(256, 2)
void tp_main(const u16_t* __restrict__ ws, float* __restrict__ out)
{
  __shared__ u16_t smem[30720];     // 60 KB: sA 32K | sBp 16K | sW 3x4K
  u16_t* sA  = smem;
  u16_t* sBp = smem + 16384;
  u16_t* sW  = smem + 24576;

  f32x4 acc[2][4];
#pragma unroll
  for (int a=0;a<2;++a)
#pragma unroll
    for (int b=0;b<4;++b) acc[a][b] = (f32x4){0.f,0.f,0.f,0.f};

  const int lane = threadIdx.x & 63, wid = threadIdx.x >> 6;
  const int q = lane >> 4, r15 = lane & 15;
  const int bid = blockIdx.x;

  if (bid < 128) {            // ---- J0a: w000 (s1 (x) s2), N-half h
    const int h = bid & 1, rt = bid >> 1;
    const u16_t* Wt = ws + OFF_W000 + (unsigned)h*(512u*2048u);
    const u16_t* s1 = ws + OFF_XS1 + rt*16384;
    const u16_t* s2 = ws + OFF_XS2 + rt*16384;
    run_phase(Wt,        4, 256, s1, 32768, s2,        false, sA,sBp,sW, acc);   // v in [0,64)
    run_phase(Wt + 4096, 4, 256, s1, 32768, s2 + 8192, false, sA,sBp,sW, acc);   // v in [64,128)
    const float sc = 0.006987712429686843f;   // A_0E
#pragma unroll
    for (int mt=0;mt<2;++mt)
#pragma unroll
      for (int nt=0;nt<4;++nt)
#pragma unroll
        for (int rg=0;rg<4;++rg) {
          int row = rt*128 + (wid<<5) + (mt<<4) + (q<<2) + rg;
          int col = (h<<6) + (nt<<4) + r15;
          atomicAdd(out + row*512 + col, sc * acc[mt][nt][rg]);
        }
  } else if (bid < 320) {     // ---- J1o: component i, w011(s1,v2_i) + w101(v1_i,s2)
    const int id = bid - 128, i = id % 3, rt = id / 3;
    const u16_t* s1  = ws + OFF_XS1 + rt*16384;
    const u16_t* s2  = ws + OFF_XS2 + rt*16384;
    const u16_t* v1i = ws + OFF_XV1 + rt*24576 + i*8192;
    const u16_t* v2i = ws + OFF_XV2 + rt*24576 + i*8192;
    run_phase(ws + OFF_W011, 2, 256, s1, 32768, v2i, false, sA,sBp,sW, acc);
    run_phase(ws + OFF_W101, 2, 256, s2, 32768, v1i, false, sA,sBp,sW, acc);
    const float sc = 0.0078125f;              // A_1O/sqrt(3) = 1/128
#pragma unroll
    for (int mt=0;mt<2;++mt)
#pragma unroll
      for (int nt=0;nt<4;++nt)
#pragma unroll
        for (int rg=0;rg<4;++rg) {
          int row = rt*128 + (wid<<5) + (mt<<4) + (q<<2) + rg;
          int col = (nt<<4) + r15;
          out[row*512 + 128 + 3*col + i] = sc * acc[mt][nt][rg];
        }
  } else if (bid < 448) {     // ---- J0b: w110' (sum_i v1_i (x) v2_i), N-half h
    const int id = bid - 320, h = id & 1, rt = id >> 1;
    const u16_t* Wt = ws + OFF_W110 + (unsigned)h*(128u*2048u);
    for (int i = 0; i < 3; ++i) {
      const u16_t* v1i = ws + OFF_XV1 + rt*24576 + i*8192;
      const u16_t* v2i = ws + OFF_XV2 + rt*24576 + i*8192;
      run_phase(Wt, 2, 128, v1i, 16384, v2i, false, sA,sBp,sW, acc);
    }
    const float sc = 0.006987712429686843f;   // A_0E (1/sqrt3 folded in weights)
#pragma unroll
    for (int mt=0;mt<2;++mt)
#pragma unroll
      for (int nt=0;nt<4;++nt)
#pragma unroll
        for (int rg=0;rg<4;++rg) {
          int row = rt*128 + (wid<<5) + (mt<<4) + (q<<2) + rg;
          int col = (h<<6) + (nt<<4) + r15;
          atomicAdd(out + row*512 + col, sc * acc[mt][nt][rg]);
        }
  } else {                    // ---- J1e: w111 cross-product component kk
    const int id = bid - 448, kk = id % 3, rt = id / 3;
    int i = kk+1; if (i>2) i-=3;
    int j = kk+2; if (j>2) j-=3;
    const u16_t* v1a = ws + OFF_XV1 + rt*24576 + i*8192;
    const u16_t* v2a = ws + OFF_XV2 + rt*24576 + j*8192;
    const u16_t* v1b = ws + OFF_XV1 + rt*24576 + j*8192;
    const u16_t* v2b = ws + OFF_XV2 + rt*24576 + i*8192;
    run_phase(ws + OFF_W111, 2, 128, v1a, 16384, v2a, false, sA,sBp,sW, acc);
    run_phase(ws + OFF_W111, 2, 128, v1b, 16384, v2b, true,  sA,sBp,sW, acc);
    const float sc = 0.011048543456039806f;   // A_1E/sqrt(6) = 1/(64*sqrt2)
#pragma unroll
    for (int mt=0;mt<2;++mt)
#pragma unroll
      for (int nt=0;nt<4;++nt)
#pragma unroll
        for (int rg=0;rg<4;++rg) {
          int row = rt*128 + (wid<<5) + (mt<<4) + (q<<2) + rg;
          int col = (nt<<4) + r15;
          out[row*512 + 320 + 3*col + kk] = sc * acc[mt][nt][rg];
        }
  }
}

extern "C" void kernel_launch(void* const* d_in, const int* in_sizes, int n_in,
                              void* d_out, int out_size, void* d_ws, size_t ws_size,
                              hipStream_t stream)
{
  const float* x1   = (const float*)d_in[0];
  const float* x2   = (const float*)d_in[1];
  const float* w000 = (const float*)d_in[2];
  const float* w011 = (const float*)d_in[3];
  const float* w101 = (const float*)d_in[4];
  const float* w110 = (const float*)d_in[5];
  const float* w111 = (const float*)d_in[6];
  float* out = (float*)d_out;
  u16_t* ws  = (u16_t*)d_ws;

  if (ws_size < (size_t)WS_USHORTS * 2) return;   // need ~17.5 MB scratch

  tile_weights_k<<<15360, 256, 0, stream>>>(w000, w011, w101, w110, w111, ws);
  tile_x_k<<<20480, 256, 0, stream>>>(x1, x2, ws);
  zero_out0_k<<<4096, 256, 0, stream>>>(out);
  tp_main<<<640, 256, 0, stream>>>(ws, out);
}

// Round 2
// 161.415 us; speedup vs baseline: 1.8531x; 1.8531x over previous
//
#include <hip/hip_runtime.h>
#include <stdint.h>

// FC tensor product as on-the-fly-A GEMMs, f16 inputs, MFMA f32_16x16x32_f16.
// A[r,(u,v)] = a[r,u]*b[r,v]: b octets live in registers for a whole phase
// (u-independent), a scalars stream through per-wave private LDS chunks,
// W tiles stream through shared LDS (triple-buffered, counted vmcnt).

typedef _Float16 f16;
typedef f16 f16x8 __attribute__((ext_vector_type(8)));
typedef float f32x4 __attribute__((ext_vector_type(4)));
typedef int i32x4 __attribute__((ext_vector_type(4)));

#define OFF_W000 0u
#define OFF_W110 2097152u
#define OFF_W011 2621440u
#define OFF_W101 3145728u
#define OFF_W111 3670016u
#define OFF_XS1  3932160u
#define OFF_XS2  4980736u
#define OFF_XV1  6029312u
#define OFF_XV2  7602176u
#define OFF_S0A  9175040u
#define OFF_S0B  10223616u
#define OFF_S1O  13369344u
#define WS_ELEMS 14942208u

#define SC_0E 0.006987712429686843f
#define SC_1O 0.0078125f
#define SC_1E 0.011048543456039806f

// ---------------- pre-kernels: retile to f16 ----------------
__global__ void tile_weights_k(const float* __restrict__ w000, const float* __restrict__ w011,
                               const float* __restrict__ w101, const float* __restrict__ w110,
                               const float* __restrict__ w111, f16* __restrict__ ws)
{
  unsigned tid = blockIdx.x*256u + threadIdx.x;
  if (tid < 2097152u) {  // W000t [vh][u][p][q][n128][8]
    unsigned e=tid&7u, n=(tid>>3)&127u, q=(tid>>10)&3u, p=(tid>>12)&1u, u=(tid>>13)&127u, vh=(tid>>20)&1u;
    unsigned v = vh*64u + p*32u + q*8u + e;
    ws[OFF_W000+tid] = (f16)w000[u*16384u + v*128u + n];
    return;
  }
  tid -= 2097152u;
  if (tid < 524288u) {   // W110t [u64][p][q][n128][8], fold 1/sqrt3
    unsigned e=tid&7u, n=(tid>>3)&127u, q=(tid>>10)&3u, p=(tid>>12)&1u, u=tid>>13;
    unsigned v = p*32u + q*8u + e;
    ws[OFF_W110+tid] = (f16)(w110[u*8192u + v*128u + n] * 0.5773502691896258f);
    return;
  }
  tid -= 524288u;
  if (tid < 524288u) {   // W011t [u128][p][q][n64][8]
    unsigned e=tid&7u, n=(tid>>3)&63u, q=(tid>>9)&3u, p=(tid>>11)&1u, u=tid>>12;
    unsigned v = p*32u + q*8u + e;
    ws[OFF_W011+tid] = (f16)w011[u*4096u + v*64u + n];
    return;
  }
  tid -= 524288u;
  if (tid < 524288u) {   // W101t [u=s2 128][p][q][n64][8]  (transposed)
    unsigned e=tid&7u, n=(tid>>3)&63u, q=(tid>>9)&3u, p=(tid>>11)&1u, u=tid>>12;
    unsigned v = p*32u + q*8u + e;   // v1 index
    ws[OFF_W101+tid] = (f16)w101[v*8192u + u*64u + n];
    return;
  }
  tid -= 524288u;
  {                      // W111t [u64][p][q][n64][8]
    unsigned e=tid&7u, n=(tid>>3)&63u, q=(tid>>9)&3u, p=(tid>>11)&1u, u=tid>>12;
    unsigned v = p*32u + q*8u + e;
    ws[OFF_W111+tid] = (f16)w111[u*4096u + v*64u + n];
  }
}

__global__ void tile_x_k(const float* __restrict__ x1, const float* __restrict__ x2,
                         f16* __restrict__ ws)
{
  unsigned tid = blockIdx.x*256u + threadIdx.x;
  if (tid < 1048576u) {  // xs1 [rt][uo16][r128][8]
    unsigned e=tid&7u, r=(tid>>3)&127u, uo=(tid>>10)&15u, rt=tid>>14;
    ws[OFF_XS1+tid] = (f16)x1[(rt*128u+r)*320u + uo*8u + e];
    return;
  }
  tid -= 1048576u;
  if (tid < 1572864u) {  // xv1 [rt][i3][ov8][r128][8]
    unsigned e=tid&7u, r=(tid>>3)&127u, ov=(tid>>10)&7u, rest=tid>>13;
    unsigned i=rest%3u, rt=rest/3u;
    ws[OFF_XV1+tid] = (f16)x1[(rt*128u+r)*320u + 128u + (ov*8u+e)*3u + i];
    return;
  }
  tid -= 1572864u;
  if (tid < 1048576u) {
    unsigned e=tid&7u, r=(tid>>3)&127u, uo=(tid>>10)&15u, rt=tid>>14;
    ws[OFF_XS2+tid] = (f16)x2[(rt*128u+r)*320u + uo*8u + e];
    return;
  }
  tid -= 1048576u;
  {
    unsigned e=tid&7u, r=(tid>>3)&127u, ov=(tid>>10)&7u, rest=tid>>13;
    unsigned i=rest%3u, rt=rest/3u;
    ws[OFF_XV2+tid] = (f16)x2[(rt*128u+r)*320u + 128u + (ov*8u+e)*3u + i];
  }
}

// ---------------- main kernel ----------------
#define GLD16(g,l) __builtin_amdgcn_global_load_lds( \
    (const __attribute__((address_space(1))) unsigned int*)(g), \
    (__attribute__((address_space(3))) unsigned int*)(l), 16, 0, 0)

#define WAITV(n) asm volatile("s_waitcnt vmcnt(" #n ")" ::: "memory")

template<int N, bool NEG>   // N = W tile column count (128 or 64)
__device__ __forceinline__ void run_phase(const f16* __restrict__ Wt, int supersteps,
    const f16* __restrict__ aW, const f16* __restrict__ bW, int bRow, int h,
    f16* sW, f16* sA, f32x4 (&acc)[4][4])
{
  constexpr int S = N/64;        // global_load_lds issues per wave per tile
  constexpr int TILE = N*32;     // f16 elems per tile
  const int lane = threadIdx.x & 63, wid = threadIdx.x >> 6;
  const int q = lane >> 4, r15 = lane & 15;
  const int steps = supersteps*16;

  // b octets for the whole phase -> registers (u-independent)
  f16x8 br[4][2];
#pragma unroll
  for (int mt=0; mt<4; ++mt)
#pragma unroll
    for (int o=0; o<2; ++o)
      br[mt][o] = *(const f16x8*)(bW + (o*4+q)*1024 + (bRow + mt*16 + r15)*8);
  // force issue+complete now so manual vmcnt counting below stays exact
#pragma unroll
  for (int mt=0; mt<4; ++mt)
#pragma unroll
    for (int o=0; o<2; ++o) {
      i32x4 tmp = __builtin_bit_cast(i32x4, br[mt][o]);
      asm volatile("" :: "v"(tmp));
    }

  auto stW = [&](int t, int buf){
#pragma unroll
    for (int c=0;c<S;++c)
      GLD16((const char*)(Wt + t*TILE + (wid*S+c)*512) + lane*16,
            (char*)(sW + buf*4096 + (wid*S+c)*512));
  };
  auto stA = [&](int uo, int buf){
    GLD16((const char*)(aW + uo*1024) + lane*16, (char*)(sA + buf*512));
  };

  stW(0,0); stA(0,0); stW(1,1);      // a(0) between the two W issues (drain order)
  asm volatile("s_waitcnt vmcnt(0)" ::: "memory");
  __builtin_amdgcn_s_barrier();
  __builtin_amdgcn_sched_barrier(0);

  int rb = 0;   // LDS buffer holding tile t
  for (int ss = 0; ss < supersteps; ++ss) {
    const f16* ab = sA + (ss&1)*512;
#pragma unroll
    for (int p = 0; p < 16; ++p) {
      const int t = ss*16 + p;
      if (t + 2 < steps) {
        if (p >= 14) { if constexpr (S==1) WAITV(2); else WAITV(3); }
        else         { if constexpr (S==1) WAITV(1); else WAITV(2); }
      } else WAITV(0);
      __builtin_amdgcn_s_barrier();
      __builtin_amdgcn_sched_barrier(0);
      int wb = rb+2; if (wb>=3) wb-=3;
      if (t + 2 < steps) stW(t+2, wb);
      if (p == 13 && ss+1 < supersteps) stA(ss+1, (ss+1)&1);

      const int ul = p>>1, par = p&1;
      f16x8 af[4];
#pragma unroll
      for (int mt=0; mt<4; ++mt) {
        f16 av = ab[(mt*16+r15)*8 + ul];
        if constexpr (NEG) av = -av;
        af[mt] = av * br[mt][par];
      }
      const f16* W = sW + rb*4096;
#pragma unroll
      for (int nt=0; nt<4; ++nt) {
        f16x8 bw = *(const f16x8*)(W + (q*N + h*64 + nt*16 + r15)*8);
#pragma unroll
        for (int mt=0; mt<4; ++mt)
          acc[mt][nt] = __builtin_amdgcn_mfma_f32_16x16x32_f16(af[mt], bw, acc[mt][nt], 0,0,0);
      }
      rb = rb+1; if (rb>=3) rb-=3;
    }
  }
  __builtin_amdgcn_s_barrier();     // protect sW/sA before next phase / epilogue
  __builtin_amdgcn_sched_barrier(0);
}

__global__ __launch_bounds__(256, 3)
void tp_main(f16* __restrict__ ws, float* __restrict__ out)
{
  __shared__ f16 smem[16384];       // 32 KB: sW 3x8KB | per-wave a 2x1KB
  f16* sW = smem;
  const int lane = threadIdx.x & 63, wid = threadIdx.x >> 6;
  f16* sA = smem + 12288 + wid*1024;
  const int q = lane >> 4, r15 = lane & 15;

  f32x4 acc[4][4];
#pragma unroll
  for (int a=0;a<4;++a)
#pragma unroll
    for (int b=0;b<4;++b) acc[a][b] = (f32x4){0.f,0.f,0.f,0.f};

  const int bid = blockIdx.x;

  if (bid < 128) {          // ---- J0a: w000, v-half vh. G0: waves 2 rgrp x 2 h
    const int rt = bid >> 1, vh = bid & 1;
    const int rgrp = wid >> 1, h = wid & 1;
    const f16* aW = ws + OFF_XS1 + rt*16384 + rgrp*512;
    const f16* bW = ws + OFF_XS2 + rt*16384 + vh*8192;
    run_phase<128,false>(ws + OFF_W000 + vh*1048576u, 16, aW, bW, rgrp*64, h, sW, sA, acc);
    const int rowb = rt*128 + rgrp*64;
    if (vh == 0) {
#pragma unroll
      for (int mt=0;mt<4;++mt)
#pragma unroll
        for (int nt=0;nt<4;++nt)
#pragma unroll
          for (int rg=0;rg<4;++rg)
            out[(rowb+mt*16+q*4+rg)*512 + h*64+nt*16+r15] = SC_0E*acc[mt][nt][rg];
    } else {
      f16* slab = ws + OFF_S0A;
#pragma unroll
      for (int mt=0;mt<4;++mt)
#pragma unroll
        for (int nt=0;nt<4;++nt)
#pragma unroll
          for (int rg=0;rg<4;++rg)
            slab[(rowb+mt*16+q*4+rg)*128 + h*64+nt*16+r15] = (f16)(SC_0E*acc[mt][nt][rg]);
    }
  } else if (bid < 224) {   // ---- J1o-a: w011 (a=s1, b=v2_i). G1: 4 rgrp
    const int id = bid-128, i = id%3, rt = id/3;
    const int rgrp = wid, ro = rgrp & 1, sub = rgrp >> 1;
    const int rtt = rt*2 + sub;
    const f16* aW = ws + OFF_XS1 + rtt*16384 + ro*512;
    const f16* bW = ws + OFF_XV2 + (rtt*3+i)*8192;
    run_phase<64,false>(ws + OFF_W011, 16, aW, bW, ro*64, 0, sW, sA, acc);
    const int rowb = rt*256 + rgrp*64;
#pragma unroll
    for (int mt=0;mt<4;++mt)
#pragma unroll
      for (int nt=0;nt<4;++nt)
#pragma unroll
        for (int rg=0;rg<4;++rg)
          out[(rowb+mt*16+q*4+rg)*512 + 128 + 3*(nt*16+r15) + i] = SC_1O*acc[mt][nt][rg];
  } else if (bid < 320) {   // ---- J1o-b: w101 (a=s2, b=v1_i) -> f16 slab
    const int id = bid-224, i = id%3, rt = id/3;
    const int rgrp = wid, ro = rgrp & 1, sub = rgrp >> 1;
    const int rtt = rt*2 + sub;
    const f16* aW = ws + OFF_XS2 + rtt*16384 + ro*512;
    const f16* bW = ws + OFF_XV1 + (rtt*3+i)*8192;
    run_phase<64,false>(ws + OFF_W101, 16, aW, bW, ro*64, 0, sW, sA, acc);
    const int rowb = rt*256 + rgrp*64;
    f16* slab = ws + OFF_S1O;
#pragma unroll
    for (int mt=0;mt<4;++mt)
#pragma unroll
      for (int nt=0;nt<4;++nt)
#pragma unroll
        for (int rg=0;rg<4;++rg)
          slab[(rowb+mt*16+q*4+rg)*192 + 3*(nt*16+r15) + i] = (f16)(SC_1O*acc[mt][nt][rg]);
  } else if (bid < 416) {   // ---- J1e: w111 cross component kk (two signed terms)
    const int id = bid-320, kk = id%3, rt = id/3;
    int i = kk+1; if (i>2) i-=3;
    int j = kk+2; if (j>2) j-=3;
    const int rgrp = wid, ro = rgrp & 1, sub = rgrp >> 1;
    const int rtt = rt*2 + sub;
    run_phase<64,false>(ws + OFF_W111, 8,
        ws + OFF_XV1 + (rtt*3+i)*8192 + ro*512, ws + OFF_XV2 + (rtt*3+j)*8192,
        ro*64, 0, sW, sA, acc);
    run_phase<64,true>(ws + OFF_W111, 8,
        ws + OFF_XV1 + (rtt*3+j)*8192 + ro*512, ws + OFF_XV2 + (rtt*3+i)*8192,
        ro*64, 0, sW, sA, acc);
    const int rowb = rt*256 + rgrp*64;
#pragma unroll
    for (int mt=0;mt<4;++mt)
#pragma unroll
      for (int nt=0;nt<4;++nt)
#pragma unroll
        for (int rg=0;rg<4;++rg)
          out[(rowb+mt*16+q*4+rg)*512 + 320 + 3*(nt*16+r15) + kk] = SC_1E*acc[mt][nt][rg];
  } else {                  // ---- J0b-i: w110' (v1_i x v2_i) -> f16 slab i
    const int id = bid-416, i = id%3, rt = id/3;
    const int rgrp = wid >> 1, h = wid & 1;
    const f16* aW = ws + OFF_XV1 + (rt*3+i)*8192 + rgrp*512;
    const f16* bW = ws + OFF_XV2 + (rt*3+i)*8192;
    run_phase<128,false>(ws + OFF_W110, 8, aW, bW, rgrp*64, h, sW, sA, acc);
    const int rowb = rt*128 + rgrp*64;
    f16* slab = ws + OFF_S0B + (unsigned)i*1048576u;
#pragma unroll
    for (int mt=0;mt<4;++mt)
#pragma unroll
      for (int nt=0;nt<4;++nt)
#pragma unroll
        for (int rg=0;rg<4;++rg)
          slab[(rowb+mt*16+q*4+rg)*128 + h*64+nt*16+r15] = (f16)(SC_0E*acc[mt][nt][rg]);
  }
}

// ---------------- epilogue: fold f16 partial slabs into out ----------------
__global__ void ep_add(const f16* __restrict__ ws, float* __restrict__ out)
{
  unsigned tid = blockIdx.x*256u + threadIdx.x;
  if (tid < 1048576u) {
    unsigned r = tid>>7, c = tid&127u;
    float s = (float)ws[OFF_S0A+tid] + (float)ws[OFF_S0B+tid]
            + (float)ws[OFF_S0B+1048576u+tid] + (float)ws[OFF_S0B+2097152u+tid];
    out[r*512u+c] += s;
  } else {
    unsigned t2 = tid - 1048576u;
    unsigned r = t2/192u, c = t2 - r*192u;
    out[r*512u+128u+c] += (float)ws[OFF_S1O+t2];
  }
}

extern "C" void kernel_launch(void* const* d_in, const int* in_sizes, int n_in,
                              void* d_out, int out_size, void* d_ws, size_t ws_size,
                              hipStream_t stream)
{
  const float* x1   = (const float*)d_in[0];
  const float* x2   = (const float*)d_in[1];
  const float* w000 = (const float*)d_in[2];
  const float* w011 = (const float*)d_in[3];
  const float* w101 = (const float*)d_in[4];
  const float* w110 = (const float*)d_in[5];
  const float* w111 = (const float*)d_in[6];
  float* out = (float*)d_out;
  f16* ws   = (f16*)d_ws;

  if (ws_size < (size_t)WS_ELEMS * 2) return;   // ~29.9 MB scratch

  tile_weights_k<<<15360, 256, 0, stream>>>(w000, w011, w101, w110, w111, ws);
  tile_x_k<<<20480, 256, 0, stream>>>(x1, x2, ws);
  tp_main<<<608, 256, 0, stream>>>(ws, out);
  ep_add<<<10240, 256, 0, stream>>>(ws, out);
}

// Round 4
// 149.165 us; speedup vs baseline: 2.0053x; 1.0821x over previous
//
#include <hip/hip_runtime.h>
#include <stdint.h>

// FC tensor product as on-the-fly-A GEMMs, f16, MFMA f32_16x16x32_f16.
// A[r,(u,v)] = a[r,u]*b[r,v]: b octets in registers all phase (u-independent),
// a octets in registers per superstep (loaded from per-wave LDS chunk),
// W pairs (2 tiles, K=64) stream through 4 LDS pair-slots, counted vmcnt,
// one barrier per 32 MFMA. Grid = 512 identical-length blocks (2/CU exactly).

typedef _Float16 f16;
typedef f16 f16x8 __attribute__((ext_vector_type(8)));
typedef float f32x4 __attribute__((ext_vector_type(4)));
typedef int i32x4 __attribute__((ext_vector_type(4)));

#define OFF_W000 0u
#define OFF_W110 2097152u
#define OFF_W011 2621440u
#define OFF_W101 3145728u
#define OFF_W111 3670016u        // size 262144 (64*64*64) -- NOT 524288
#define OFF_XS1  3932160u
#define OFF_XS2  4980736u
#define OFF_XV1  6029312u
#define OFF_XV2  7602176u
#define OFF_S0A  9175040u
#define OFF_S0B  10223616u
#define OFF_S1O  13369344u
#define WS_ELEMS 14942208u

#define SC_0E 0.006987712429686843f
#define SC_1O 0.0078125f
#define SC_1E 0.011048543456039806f

// ---------------- pre-kernel: retile everything to f16 ----------------
// total threads = 9175040 = 35840 blocks * 256 (exact; every branch bound exact)
__global__ void tile_all_k(const float* __restrict__ w000, const float* __restrict__ w011,
                           const float* __restrict__ w101, const float* __restrict__ w110,
                           const float* __restrict__ w111, const float* __restrict__ x1,
                           const float* __restrict__ x2, f16* __restrict__ ws)
{
  unsigned tid = blockIdx.x*256u + threadIdx.x;
  if (tid < 2097152u) {  // W000t [vh][u][p][q][n128][8]
    unsigned e=tid&7u, n=(tid>>3)&127u, q=(tid>>10)&3u, p=(tid>>12)&1u, u=(tid>>13)&127u, vh=(tid>>20)&1u;
    unsigned v = vh*64u + p*32u + q*8u + e;
    ws[OFF_W000+tid] = (f16)w000[u*16384u + v*128u + n];
    return;
  }
  tid -= 2097152u;
  if (tid < 524288u) {   // W110t [u64][p][q][n128][8], fold 1/sqrt3
    unsigned e=tid&7u, n=(tid>>3)&127u, q=(tid>>10)&3u, p=(tid>>12)&1u, u=tid>>13;
    unsigned v = p*32u + q*8u + e;
    ws[OFF_W110+tid] = (f16)(w110[u*8192u + v*128u + n] * 0.5773502691896258f);
    return;
  }
  tid -= 524288u;
  if (tid < 524288u) {   // W011t [u128][p][q][n64][8]
    unsigned e=tid&7u, n=(tid>>3)&63u, q=(tid>>9)&3u, p=(tid>>11)&1u, u=tid>>12;
    unsigned v = p*32u + q*8u + e;
    ws[OFF_W011+tid] = (f16)w011[u*4096u + v*64u + n];
    return;
  }
  tid -= 524288u;
  if (tid < 524288u) {   // W101t [u=s2 128][p][q][n64][8]  (transposed)
    unsigned e=tid&7u, n=(tid>>3)&63u, q=(tid>>9)&3u, p=(tid>>11)&1u, u=tid>>12;
    unsigned v = p*32u + q*8u + e;   // v1 index
    ws[OFF_W101+tid] = (f16)w101[v*8192u + u*64u + n];
    return;
  }
  tid -= 524288u;
  if (tid < 262144u) {   // W111t [u64][p][q][n64][8]  (exact size 64*64*64)
    unsigned e=tid&7u, n=(tid>>3)&63u, q=(tid>>9)&3u, p=(tid>>11)&1u, u=tid>>12;
    unsigned v = p*32u + q*8u + e;
    ws[OFF_W111+tid] = (f16)w111[u*4096u + v*64u + n];
    return;
  }
  tid -= 262144u;
  if (tid < 1048576u) {  // xs1 [rt][uo16][r128][8]
    unsigned e=tid&7u, r=(tid>>3)&127u, uo=(tid>>10)&15u, rt=tid>>14;
    ws[OFF_XS1+tid] = (f16)x1[(rt*128u+r)*320u + uo*8u + e];
    return;
  }
  tid -= 1048576u;
  if (tid < 1572864u) {  // xv1 [rt][i3][ov8][r128][8]
    unsigned e=tid&7u, r=(tid>>3)&127u, ov=(tid>>10)&7u, rest=tid>>13;
    unsigned i=rest%3u, rt=rest/3u;
    ws[OFF_XV1+tid] = (f16)x1[(rt*128u+r)*320u + 128u + (ov*8u+e)*3u + i];
    return;
  }
  tid -= 1572864u;
  if (tid < 1048576u) {  // xs2
    unsigned e=tid&7u, r=(tid>>3)&127u, uo=(tid>>10)&15u, rt=tid>>14;
    ws[OFF_XS2+tid] = (f16)x2[(rt*128u+r)*320u + uo*8u + e];
    return;
  }
  tid -= 1048576u;
  {                      // xv2 (exactly 1572864 remain)
    unsigned e=tid&7u, r=(tid>>3)&127u, ov=(tid>>10)&7u, rest=tid>>13;
    unsigned i=rest%3u, rt=rest/3u;
    ws[OFF_XV2+tid] = (f16)x2[(rt*128u+r)*320u + 128u + (ov*8u+e)*3u + i];
  }
}

// ---------------- main kernel ----------------
#define GLD16(g,l) __builtin_amdgcn_global_load_lds( \
    (const __attribute__((address_space(1))) unsigned int*)(g), \
    (__attribute__((address_space(3))) unsigned int*)(l), 16, 0, 0)

#define WAITV(n) asm volatile("s_waitcnt vmcnt(" #n ")" ::: "memory")

// One phase: acc += A*W.  SS supersteps; each superstep = 8 pair-macros;
// pair-macro = 2 K-tiles of 32 (u = macro index, both v-parities).
template<int N, bool NEG, int SS>   // N = W tile col count (128 or 64)
__device__ __forceinline__ void run_phase(const f16* __restrict__ Wt,
    const f16* __restrict__ aW, const f16* __restrict__ bW, int bRow, int h,
    f16* sW, f16* sAw, f32x4 (&acc)[4][4])
{
  constexpr int S     = N/64;      // GLD16 issues per wave per tile
  constexpr int TILEB = N*64;      // tile bytes
  constexpr int PAIRB = 2*TILEB;   // pair bytes
  constexpr int TILEE = N*32;      // tile f16 elems
  constexpr int PAIRE = 2*TILEE;
  constexpr int M     = SS*8;      // pair-macros
  const int lane = threadIdx.x & 63, wid = threadIdx.x >> 6;
  const int q = lane >> 4, r15 = lane & 15;

  WAITV(0);   // clear outstanding vmem (prior phase's stores etc) for exact counting

  // b octets for the whole phase -> registers (u-independent)
  f16x8 br[4][2];
#pragma unroll
  for (int mt=0; mt<4; ++mt)
#pragma unroll
    for (int o=0; o<2; ++o)
      br[mt][o] = *(const f16x8*)(bW + (o*4+q)*1024 + (bRow + mt*16 + r15)*8);
#pragma unroll
  for (int mt=0; mt<4; ++mt)
#pragma unroll
    for (int o=0; o<2; ++o) {      // force loads complete now (vmcnt -> 0)
      i32x4 tmp = __builtin_bit_cast(i32x4, br[mt][o]);
      asm volatile("" :: "v"(tmp));
    }

  const int wchunk = wid*S*1024;
  auto stPair = [&](int p, int slot){
    const char* s = (const char*)Wt + (size_t)p*PAIRB + wchunk;
    char* d = (char*)sW + slot*PAIRB + wchunk;
#pragma unroll
    for (int tt=0; tt<2; ++tt)
#pragma unroll
      for (int c=0; c<S; ++c)
        GLD16(s + tt*TILEB + c*1024 + lane*16, d + tt*TILEB + c*1024);
  };
  auto stA = [&](int ss2){   // 1KB a-chunk for superstep ss2 into per-wave slot
    GLD16((const char*)(aW + ss2*1024) + lane*16, (char*)sAw + (ss2&1)*1024);
  };

  stA(0); stPair(0,0); stPair(1,1);   // FIFO: a0, pair0, pair1

#pragma unroll 1
  for (int ss = 0; ss < SS; ++ss) {
    f16x8 aR[4];
#pragma unroll
    for (int k = 0; k < 8; ++k) {
      const int m = ss*8 + k;
      // ---- counted wait: leave next pair (+pending stA at k==7) in flight
      if (k == 7) {
        if (ss+1 < SS) { if constexpr (S==1) WAITV(3); else WAITV(5); }
        else           WAITV(0);
      } else {
        if constexpr (S==1) WAITV(2); else WAITV(4);
      }
      __builtin_amdgcn_s_barrier();
      __builtin_amdgcn_sched_barrier(0);
      // ---- issues (order matters for vmcnt FIFO: stA before stPair)
      if (k == 6 && ss+1 < SS) stA(ss+1);
      if (m+2 < M) stPair(m+2, (k+2)&3);
      // ---- a octets for this superstep (chunk just guaranteed resident)
      if (k == 0) {
#pragma unroll
        for (int mt=0; mt<4; ++mt)
          aR[mt] = *(const f16x8*)(sAw + (ss&1)*512 + (mt*16+r15)*8);
      }
      // ---- A fragments: scalar a (elem k, static) x b octets
      f16x8 af[4][2];
#pragma unroll
      for (int mt=0; mt<4; ++mt) {
        f16 av = aR[mt][k];
        if constexpr (NEG) av = -av;
        af[mt][0] = av * br[mt][0];
        af[mt][1] = av * br[mt][1];
      }
      // ---- 32 MFMA on pair-slot k&3
#pragma unroll
      for (int tt=0; tt<2; ++tt) {
        const f16* W = sW + (k&3)*PAIRE + tt*TILEE;
#pragma unroll
        for (int nt=0; nt<4; ++nt) {
          f16x8 bw = *(const f16x8*)(W + (q*N + h*64 + nt*16 + r15)*8);
#pragma unroll
          for (int mt=0; mt<4; ++mt)
            acc[mt][nt] = __builtin_amdgcn_mfma_f32_16x16x32_f16(af[mt][tt], bw, acc[mt][nt], 0,0,0);
        }
      }
    }
  }
  __builtin_amdgcn_s_barrier();     // protect sW/sA before next phase / epilogue
  __builtin_amdgcn_sched_barrier(0);
}

__global__ __launch_bounds__(256, 2)
void tp_main(f16* __restrict__ ws, float* __restrict__ out)
{
  __shared__ f16 smem[36864];       // 72KB: sW 4 pair-slots x 16KB | per-wave a 2x1KB
  f16* sW = smem;
  const int lane = threadIdx.x & 63, wid = threadIdx.x >> 6;
  f16* sAw = smem + 32768 + wid*1024;
  const int q = lane >> 4, r15 = lane & 15;

  f32x4 acc[4][4];
#pragma unroll
  for (int a=0;a<4;++a)
#pragma unroll
    for (int b=0;b<4;++b) acc[a][b] = (f32x4){0.f,0.f,0.f,0.f};

  const int bid = blockIdx.x;

  if (bid < 128) {          // ---- J0a: w000, v-half vh. waves: 2 rgrp x 2 h
    const int rt = bid >> 1, vh = bid & 1;
    const int rgrp = wid >> 1, h = wid & 1;
    const f16* aW = ws + OFF_XS1 + rt*16384 + rgrp*512;
    const f16* bW = ws + OFF_XS2 + rt*16384 + vh*8192;
    run_phase<128,false,16>(ws + OFF_W000 + vh*1048576u, aW, bW, rgrp*64, h, sW, sAw, acc);
    const int rowb = rt*128 + rgrp*64;
    if (vh == 0) {
#pragma unroll
      for (int mt=0;mt<4;++mt)
#pragma unroll
        for (int nt=0;nt<4;++nt)
#pragma unroll
          for (int rg=0;rg<4;++rg)
            out[(rowb+mt*16+q*4+rg)*512 + h*64+nt*16+r15] = SC_0E*acc[mt][nt][rg];
    } else {
      f16* slab = ws + OFF_S0A;
#pragma unroll
      for (int mt=0;mt<4;++mt)
#pragma unroll
        for (int nt=0;nt<4;++nt)
#pragma unroll
          for (int rg=0;rg<4;++rg)
            slab[(rowb+mt*16+q*4+rg)*128 + h*64+nt*16+r15] = (f16)(SC_0E*acc[mt][nt][rg]);
    }
  } else if (bid < 224) {   // ---- J1o-a: w011 (a=s1, b=v2_i), 4 row-groups
    const int id = bid-128, i = id%3, rt = id/3;
    const int rgrp = wid, ro = rgrp & 1, sub = rgrp >> 1;
    const int rtt = rt*2 + sub;
    const f16* aW = ws + OFF_XS1 + rtt*16384 + ro*512;
    const f16* bW = ws + OFF_XV2 + (rtt*3+i)*8192;
    run_phase<64,false,16>(ws + OFF_W011, aW, bW, ro*64, 0, sW, sAw, acc);
    const int rowb = rt*256 + rgrp*64;
#pragma unroll
    for (int mt=0;mt<4;++mt)
#pragma unroll
      for (int nt=0;nt<4;++nt)
#pragma unroll
        for (int rg=0;rg<4;++rg)
          out[(rowb+mt*16+q*4+rg)*512 + 128 + 3*(nt*16+r15) + i] = SC_1O*acc[mt][nt][rg];
  } else if (bid < 320) {   // ---- J1o-b: w101 (a=s2, b=v1_i) -> f16 slab
    const int id = bid-224, i = id%3, rt = id/3;
    const int rgrp = wid, ro = rgrp & 1, sub = rgrp >> 1;
    const int rtt = rt*2 + sub;
    const f16* aW = ws + OFF_XS2 + rtt*16384 + ro*512;
    const f16* bW = ws + OFF_XV1 + (rtt*3+i)*8192;
    run_phase<64,false,16>(ws + OFF_W101, aW, bW, ro*64, 0, sW, sAw, acc);
    const int rowb = rt*256 + rgrp*64;
    f16* slab = ws + OFF_S1O;
#pragma unroll
    for (int mt=0;mt<4;++mt)
#pragma unroll
      for (int nt=0;nt<4;++nt)
#pragma unroll
        for (int rg=0;rg<4;++rg)
          slab[(rowb+mt*16+q*4+rg)*192 + 3*(nt*16+r15) + i] = (f16)(SC_1O*acc[mt][nt][rg]);
  } else if (bid < 416) {   // ---- J1e: w111 cross component kk (two signed terms)
    const int id = bid-320, kk = id%3, rt = id/3;
    int i = kk+1; if (i>2) i-=3;
    int j = kk+2; if (j>2) j-=3;
    const int rgrp = wid, ro = rgrp & 1, sub = rgrp >> 1;
    const int rtt = rt*2 + sub;
    run_phase<64,false,8>(ws + OFF_W111,
        ws + OFF_XV1 + (rtt*3+i)*8192 + ro*512, ws + OFF_XV2 + (rtt*3+j)*8192,
        ro*64, 0, sW, sAw, acc);
    run_phase<64,true,8>(ws + OFF_W111,
        ws + OFF_XV1 + (rtt*3+j)*8192 + ro*512, ws + OFF_XV2 + (rtt*3+i)*8192,
        ro*64, 0, sW, sAw, acc);
    const int rowb = rt*256 + rgrp*64;
#pragma unroll
    for (int mt=0;mt<4;++mt)
#pragma unroll
      for (int nt=0;nt<4;++nt)
#pragma unroll
        for (int rg=0;rg<4;++rg)
          out[(rowb+mt*16+q*4+rg)*512 + 320 + 3*(nt*16+r15) + kk] = SC_1E*acc[mt][nt][rg];
  } else {                  // ---- J0b: w110' (v1_i x v2_i), two rt per block
    const int id = bid-416, i = id%3, rp = id/3;
    const int rgrp = wid >> 1, h = wid & 1;
#pragma unroll 1
    for (int hh = 0; hh < 2; ++hh) {
      const int rt = rp*2 + hh;
      const f16* aW = ws + OFF_XV1 + (rt*3+i)*8192 + rgrp*512;
      const f16* bW = ws + OFF_XV2 + (rt*3+i)*8192;
      run_phase<128,false,8>(ws + OFF_W110, aW, bW, rgrp*64, h, sW, sAw, acc);
      const int rowb = rt*128 + rgrp*64;
      f16* slab = ws + OFF_S0B + (unsigned)i*1048576u;
#pragma unroll
      for (int mt=0;mt<4;++mt)
#pragma unroll
        for (int nt=0;nt<4;++nt)
#pragma unroll
          for (int rg=0;rg<4;++rg) {
            slab[(rowb+mt*16+q*4+rg)*128 + h*64+nt*16+r15] = (f16)(SC_0E*acc[mt][nt][rg]);
            acc[mt][nt][rg] = 0.f;
          }
    }
  }
}

// ---------------- epilogue: fold f16 partial slabs into out ----------------
__global__ void ep_add(const f16* __restrict__ ws, float* __restrict__ out)
{
  unsigned tid = blockIdx.x*256u + threadIdx.x;
  if (tid < 1048576u) {
    unsigned r = tid>>7, c = tid&127u;
    float s = (float)ws[OFF_S0A+tid] + (float)ws[OFF_S0B+tid]
            + (float)ws[OFF_S0B+1048576u+tid] + (float)ws[OFF_S0B+2097152u+tid];
    out[r*512u+c] += s;
  } else {
    unsigned t2 = tid - 1048576u;
    unsigned r = t2/192u, c = t2 - r*192u;
    out[r*512u+128u+c] += (float)ws[OFF_S1O+t2];
  }
}

extern "C" void kernel_launch(void* const* d_in, const int* in_sizes, int n_in,
                              void* d_out, int out_size, void* d_ws, size_t ws_size,
                              hipStream_t stream)
{
  const float* x1   = (const float*)d_in[0];
  const float* x2   = (const float*)d_in[1];
  const float* w000 = (const float*)d_in[2];
  const float* w011 = (const float*)d_in[3];
  const float* w101 = (const float*)d_in[4];
  const float* w110 = (const float*)d_in[5];
  const float* w111 = (const float*)d_in[6];
  float* out = (float*)d_out;
  f16* ws   = (f16*)d_ws;

  if (ws_size < (size_t)WS_ELEMS * 2) return;   // ~29.9 MB scratch

  tile_all_k<<<35840, 256, 0, stream>>>(w000, w011, w101, w110, w111, x1, x2, ws);
  tp_main<<<512, 256, 0, stream>>>(ws, out);
  ep_add<<<10240, 256, 0, stream>>>(ws, out);
}